// Round 10
// baseline (229.555 us; speedup 1.0000x reference)
//
#include <hip/hip_runtime.h>
#include <stdint.h>

#define D     512
#define NSUP  5000   // 1000 classes * 5 shots
#define NQRY  5000
#define NPAD  5120   // 20 tiles of 256
#define SCALE 512.0f

// ---------------- ws layout (bytes) ----------------
#define OFF_SHI     0
#define OFF_SLO     5242880
#define OFF_QHI     10485760
#define OFF_QLO     15728640
#define OFF_PARTIAL 20971520
#define OFF_MEAN    21176320
#define OFF_KEYS    21178368
#define OFF_CTR     21218368   // 2 x u32 (zeroed via hipMemsetAsync each launch)

// ---------------- dynamic LDS layout (bytes) ----------------
#define SH_SHI   0
#define SH_SLO   32768
#define SH_QHI   65536
#define SH_QLO   98304
#define SH_KL    131072
#define SH_DM    133120
#define SH_TOTAL 133136

typedef _Float16 half4v __attribute__((ext_vector_type(4)));
typedef _Float16 half8v __attribute__((ext_vector_type(8)));
typedef float    f32x4  __attribute__((ext_vector_type(4)));

__device__ __forceinline__ unsigned long long pack_key(float v, int sidx) {
    unsigned u = __float_as_uint(v);
    u = (u & 0x80000000u) ? ~u : (u | 0x80000000u);   // monotone float->uint
    return ((unsigned long long)u << 32) | (unsigned)(0xFFFFFFFFu - (unsigned)sidx);
}

__device__ __forceinline__ void gload16(const void* g, void* l) {
    __builtin_amdgcn_global_load_lds(
        (const __attribute__((address_space(1))) unsigned int*)g,
        (__attribute__((address_space(3))) unsigned int*)l, 16, 0, 0);
}

// K1: fused mean pipeline — partial col sums (100 blocks), zero keys,
// last block (device-scope counter) finishes the mean in fixed order.
__global__ void k_prep(const float* __restrict__ sup, float* __restrict__ partial,
                       float* __restrict__ mean, unsigned long long* __restrict__ keys,
                       unsigned int* __restrict__ ctr) {
    const int col = threadIdx.x;           // 512
    const int b   = blockIdx.x;            // 100
    float acc = 0.0f;
    #pragma unroll 5
    for (int r = 0; r < 50; ++r)
        acc += sup[(size_t)(b * 50 + r) * D + col];
    partial[b * D + col] = acc;
    if (col < 50) keys[b * 50 + col] = 0ull;
    __threadfence();                       // publish partial+keys (agent scope)
    __syncthreads();
    __shared__ unsigned int done;
    if (col == 0)
        done = __hip_atomic_fetch_add(ctr, 1u, __ATOMIC_ACQ_REL, __HIP_MEMORY_SCOPE_AGENT);
    __syncthreads();
    if (done == 99) {                      // last block: deterministic fixed-order sum
        float m = 0.0f;
        #pragma unroll 4
        for (int bb = 0; bb < 100; ++bb)
            m += __hip_atomic_load(&partial[bb * D + col],
                                   __ATOMIC_RELAXED, __HIP_MEMORY_SCOPE_AGENT);
        mean[col] = m * (1.0f / (float)NSUP);
    }
}

// K2: center + L2-normalize + scale by 512 + split into fp16 hi/lo.
__global__ void k_split(const float* __restrict__ sup, const float* __restrict__ qry,
                        const float* __restrict__ mean,
                        _Float16* __restrict__ shi, _Float16* __restrict__ slo,
                        _Float16* __restrict__ qhi, _Float16* __restrict__ qlo) {
    const int t    = threadIdx.x;
    const int rloc = t >> 7;               // row within block, 0..3
    const int tc   = t & 127;              // 128 threads per row
    const int b    = (int)blockIdx.x * 4 + rloc;   // global row id 0..10239
    const float* src; _Float16 *dhi, *dlo; int valid;
    if (b < NPAD) { src = sup + (size_t)b * D;
                    dhi = shi + (size_t)b * D; dlo = slo + (size_t)b * D; valid = (b < NSUP); }
    else          { int r = b - NPAD; src = qry + (size_t)r * D;
                    dhi = qhi + (size_t)r * D; dlo = qlo + (size_t)r * D; valid = (r < NQRY); }
    __shared__ float red[8];
    if (!valid) {
        half4v z = {};
        *(half4v*)(dhi + tc * 4) = z;
        *(half4v*)(dlo + tc * 4) = z;
        return;
    }
    float4 v = *(const float4*)(src + tc * 4);
    float4 m = *(const float4*)(mean + tc * 4);
    v.x -= m.x; v.y -= m.y; v.z -= m.z; v.w -= m.w;
    float ss = v.x * v.x + v.y * v.y + v.z * v.z + v.w * v.w;
    #pragma unroll
    for (int off = 32; off > 0; off >>= 1) ss += __shfl_down(ss, off, 64);
    if ((t & 63) == 0) red[t >> 6] = ss;
    __syncthreads();
    const float rn = SCALE / sqrtf(red[rloc * 2] + red[rloc * 2 + 1]);
    float sv[4] = {v.x * rn, v.y * rn, v.z * rn, v.w * rn};
    half4v h, l;
    #pragma unroll
    for (int i = 0; i < 4; ++i) {
        _Float16 hh = (_Float16)sv[i];
        h[i] = hh;
        l[i] = (_Float16)(sv[i] - (float)hh);
    }
    *(half4v*)(dhi + tc * 4) = h;
    *(half4v*)(dlo + tc * 4) = l;
}

// K3: 256x256 tile, 8 waves, wave tile 128x64, BK=32, dbuf LDS (0 conflicts).
// R8's term-ordered counted-vmcnt schedule (best measured: 84.3us, MfmaUtil 41%)
// + peeled last tile (no wrap restage) + fused last-block decode.
__launch_bounds__(512, 2)
__global__ void k_main(const _Float16* __restrict__ shi, const _Float16* __restrict__ slo,
                       const _Float16* __restrict__ qhi, const _Float16* __restrict__ qlo,
                       unsigned long long* __restrict__ keys, int* __restrict__ out,
                       unsigned int* __restrict__ ctr) {
    extern __shared__ char smem[];
    char* lshi = smem + SH_SHI;
    char* lslo = smem + SH_SLO;
    char* lqhi = smem + SH_QHI;
    char* lqlo = smem + SH_QLO;
    unsigned long long* kl = (unsigned long long*)(smem + SH_KL);

    const int tid  = threadIdx.x;
    const int lane = tid & 63;
    const int wv   = tid >> 6;            // 8 waves
    const int q0   = blockIdx.x * 256;
    const int s0   = blockIdx.y * 256;
    const int wr   = wv >> 2;             // support half 0/1
    const int wc   = wv & 3;              // query col 0..3

    if (tid < 256) kl[tid] = 0ull;

    // ---- staging addresses (verified R4/R5/R8) ----
    const int srow = wv * 16 + (lane >> 2);                 // chunk0 row 0..127
    const int sl0  = ((lane & 3) ^ ((lane >> 3) & 3)) * 16;
    const size_t gA0 = (size_t)(s0 + srow) * 1024 + sl0;    // +131072 -> rows 128..255
    const size_t gB0 = (size_t)(q0 + srow) * 1024 + sl0;
    const char* pShi = (const char*)shi; const char* pSlo = (const char*)slo;
    const char* pQhi = (const char*)qhi; const char* pQlo = (const char*)qlo;
    const int dst0 = wv * 1024;           // wave-uniform LDS dest (+lane*16 by HW)
    const int dst1 = 8192 + wv * 1024;

    // ---- fragment read bases (verified R4/R5/R8) ----
    const int l15 = lane & 15;
    const int kg  = lane >> 4;
    const int swz = (kg ^ ((l15 >> 1) & 3)) * 16;
    const int foA = (wr * 128 + l15) * 64 + swz;   // + fa*1024 + P*16384
    const int foB = (wc * 64  + l15) * 64 + swz;   // + fb*1024 + P*16384

    f32x4 acc[8][4] = {};

#define BAR()    asm volatile("s_barrier" ::: "memory")
#define WAITV6() asm volatile("s_waitcnt vmcnt(6)" ::: "memory")
#define WAITV4() asm volatile("s_waitcnt vmcnt(4)" ::: "memory")
#define WAITV2() asm volatile("s_waitcnt vmcnt(2)" ::: "memory")
#define WAITV0() asm volatile("s_waitcnt vmcnt(0)" ::: "memory")

// stage pair k (k: 0=Shi 1=Slo 2=Qhi 3=Qlo) of tile KT into buffer P
#define ST2(P, KT, K2) do { const size_t kb_ = (size_t)(KT) * 64;           \
        if ((K2) == 0) {                                                    \
            gload16(pShi + gA0 + kb_,          lshi + (P) * 16384 + dst0);  \
            gload16(pShi + gA0 + 131072 + kb_, lshi + (P) * 16384 + dst1);  \
        } else if ((K2) == 1) {                                             \
            gload16(pSlo + gA0 + kb_,          lslo + (P) * 16384 + dst0);  \
            gload16(pSlo + gA0 + 131072 + kb_, lslo + (P) * 16384 + dst1);  \
        } else if ((K2) == 2) {                                             \
            gload16(pQhi + gB0 + kb_,          lqhi + (P) * 16384 + dst0);  \
            gload16(pQhi + gB0 + 131072 + kb_, lqhi + (P) * 16384 + dst1);  \
        } else {                                                            \
            gload16(pQlo + gB0 + kb_,          lqlo + (P) * 16384 + dst0);  \
            gload16(pQlo + gB0 + 131072 + kb_, lqlo + (P) * 16384 + dst1);  \
        } } while (0)

#define RD_AH(P) do { _Pragma("unroll") for (int f = 0; f < 8; ++f)         \
        ah[f] = *(const half8v*)(lshi + (P) * 16384 + foA + f * 1024); } while (0)
#define RD_AL(P) do { _Pragma("unroll") for (int f = 0; f < 8; ++f)         \
        al[f] = *(const half8v*)(lslo + (P) * 16384 + foA + f * 1024); } while (0)
#define RD_BH(P) do { _Pragma("unroll") for (int j = 0; j < 4; ++j)         \
        bh[j] = *(const half8v*)(lqhi + (P) * 16384 + foB + j * 1024); } while (0)
#define RD_BL(P) do { _Pragma("unroll") for (int j = 0; j < 4; ++j)         \
        bl[j] = *(const half8v*)(lqlo + (P) * 16384 + foB + j * 1024); } while (0)

// 32 MFMA: one term (A-array AV x B-array BV) over full wave tile
#define MMA32(AV, BV) do {                                                  \
        __builtin_amdgcn_s_setprio(1);                                      \
        _Pragma("unroll")                                                   \
        for (int fa_ = 0; fa_ < 8; ++fa_)                                   \
        { _Pragma("unroll")                                                 \
          for (int fb_ = 0; fb_ < 4; ++fb_) {                               \
            acc[fa_][fb_] = __builtin_amdgcn_mfma_f32_16x16x32_f16(         \
                AV[fa_], BV[fb_], acc[fa_][fb_], 0, 0, 0);                  \
          } }                                                               \
        __builtin_amdgcn_s_setprio(0);                                      \
        __builtin_amdgcn_sched_barrier(0);                                  \
    } while (0)

    // prologue: stage tile 0 (order Shi,Qhi,Slo,Qlo); certify Shi+Qhi (4 in flight)
    ST2(0, 0, 0); ST2(0, 0, 2); ST2(0, 0, 1); ST2(0, 0, 3);
    WAITV4();
    BAR();

    for (int t = 0; t < 15; ++t) {        // tiles 0..14; tile 15 peeled below
        const int P  = t & 1;
        const int Pn = P ^ 1;
        const int tn = t + 1;
        half8v ah[8], al[8], bh[4], bl[4];

        // ph_hh: hi*hi (Shi,Qhi certified at entry)
        RD_AH(P); RD_BH(P);
        ST2(Pn, tn, 0); ST2(Pn, tn, 2);   // Shi,Qhi(t+1)  (in-flight: 8)
        MMA32(ah, bh);
        WAITV6();                         // certify Slo(t)
        BAR();
        // ph_lh: lo*hi (bh kept)
        RD_AL(P);
        ST2(Pn, tn, 1);                   // Slo(t+1)      (in-flight: 8)
        MMA32(al, bh);
        WAITV6();                         // certify Qlo(t)
        BAR();
        // ph_hl: hi*lo (ah kept)
        RD_BL(P);
        ST2(Pn, tn, 3);                   // Qlo(t+1)      (in-flight: 8)
        MMA32(ah, bl);
        WAITV4();                         // certify Shi,Qhi(t+1); 4 stay in flight
        BAR();
    }
    {   // peeled tile 15 (P=1): no staging; entry in-flight = 4 (Slo15,Qlo15)
        half8v ah[8], al[8], bh[4], bl[4];
        RD_AH(1); RD_BH(1);
        MMA32(ah, bh);
        WAITV2();                         // certify Slo(15); 2 remain
        BAR();
        RD_AL(1);
        MMA32(al, bh);
        WAITV0();                         // certify Qlo(15); drained
        BAR();
        RD_BL(1);
        MMA32(ah, bl);
    }

#undef MMA32
#undef RD_BL
#undef RD_BH
#undef RD_AL
#undef RD_AH
#undef ST2

    // ---- fused argmax epilogue (verified mapping) ----
    // col(query) = wc*64 + fb*16 + l15 ; row(support) = wr*128 + fa*16 + kg*4 + r
    #pragma unroll
    for (int fb = 0; fb < 4; ++fb) {
        unsigned long long best = 0ull;
        #pragma unroll
        for (int fa = 0; fa < 8; ++fa)
            #pragma unroll
            for (int r = 0; r < 4; ++r) {
                const int s = s0 + wr * 128 + fa * 16 + kg * 4 + r;
                if (s < NSUP) {
                    unsigned long long k = pack_key(acc[fa][fb][r], s);
                    if (k > best) best = k;
                }
            }
        unsigned long long o = __shfl_xor(best, 16, 64); if (o > best) best = o;
        o = __shfl_xor(best, 32, 64);                    if (o > best) best = o;
        if (kg == 0) atomicMax(&kl[wc * 64 + fb * 16 + l15], best);
    }
    __syncthreads();
    if (tid < 256) {
        const int q = q0 + tid;
        if (q < NQRY && kl[tid] != 0ull) atomicMax(&keys[q], kl[tid]);
    }

    // ---- fused decode: last finishing block decodes all keys ----
    __syncthreads();                      // block's key atomics complete
    __threadfence();                      // publish (agent scope)
    unsigned int* dmark = (unsigned int*)(smem + SH_DM);
    if (tid == 0)
        *dmark = __hip_atomic_fetch_add(ctr, 1u, __ATOMIC_ACQ_REL, __HIP_MEMORY_SCOPE_AGENT);
    __syncthreads();
    if (*dmark == (unsigned)(gridDim.x * gridDim.y - 1)) {
        for (int q = tid; q < NQRY; q += 512) {
            unsigned long long kv = __hip_atomic_load(&keys[q], __ATOMIC_RELAXED,
                                                      __HIP_MEMORY_SCOPE_AGENT);
            unsigned sidx = 0xFFFFFFFFu - (unsigned)(kv & 0xFFFFFFFFull);
            out[q] = (int)(sidx / 5u);
        }
    }
#undef BAR
#undef WAITV6
#undef WAITV4
#undef WAITV2
#undef WAITV0
}

extern "C" void kernel_launch(void* const* d_in, const int* in_sizes, int n_in,
                              void* d_out, int out_size, void* d_ws, size_t ws_size,
                              hipStream_t stream) {
    const float* sup = (const float*)d_in[0];   // [1000,5,512]
    const float* qry = (const float*)d_in[1];   // [5000,512]
    // d_in[2] = use_cosine: after normalization argmin-euclid == argmax-cosine.
    int* out = (int*)d_out;

    char* ws = (char*)d_ws;
    _Float16* shi = (_Float16*)(ws + OFF_SHI);
    _Float16* slo = (_Float16*)(ws + OFF_SLO);
    _Float16* qhi = (_Float16*)(ws + OFF_QHI);
    _Float16* qlo = (_Float16*)(ws + OFF_QLO);
    float* partial = (float*)(ws + OFF_PARTIAL);
    float* mean    = (float*)(ws + OFF_MEAN);
    unsigned long long* keys = (unsigned long long*)(ws + OFF_KEYS);
    unsigned int* ctr        = (unsigned int*)(ws + OFF_CTR);

    static bool attr_set = false;
    if (!attr_set) {
        (void)hipFuncSetAttribute((const void*)k_main,
                                  hipFuncAttributeMaxDynamicSharedMemorySize, SH_TOTAL);
        attr_set = true;
    }

    // zero the 2 completion counters (ws is re-poisoned before every launch)
    (void)hipMemsetAsync(ctr, 0, 8, stream);

    k_prep<<<100, 512, 0, stream>>>(sup, partial, mean, keys, ctr);
    k_split<<<(2 * NPAD) / 4, 512, 0, stream>>>(sup, qry, mean, shi, slo, qhi, qlo);
    dim3 grid(NPAD / 256, NPAD / 256);
    k_main<<<grid, 512, SH_TOTAL, stream>>>(shi, slo, qhi, qlo, keys, out, ctr + 1);
}

// Round 11
// 158.142 us; speedup vs baseline: 1.4516x; 1.4516x over previous
//
#include <hip/hip_runtime.h>
#include <stdint.h>

#define D     512
#define NSUP  5000   // 1000 classes * 5 shots
#define NQRY  5000
#define NPAD  5120   // 20 tiles of 256
#define MEAN_BLOCKS 100
#define ROWS_PER_MEAN_BLOCK 50
#define SCALE 512.0f

// ---------------- ws layout (bytes) ----------------
#define OFF_SHI     0
#define OFF_SLO     5242880
#define OFF_QHI     10485760
#define OFF_QLO     15728640
#define OFF_PARTIAL 20971520
#define OFF_MEAN    21176320
#define OFF_KEYS    21178368

// ---------------- dynamic LDS layout (bytes) ----------------
#define SH_SHI   0
#define SH_SLO   32768
#define SH_QHI   65536
#define SH_QLO   98304
#define SH_KL    131072
#define SH_TOTAL (131072 + 2048)

typedef _Float16 half4v __attribute__((ext_vector_type(4)));
typedef _Float16 half8v __attribute__((ext_vector_type(8)));
typedef float    f32x4  __attribute__((ext_vector_type(4)));

__device__ __forceinline__ unsigned long long pack_key(float v, int sidx) {
    unsigned u = __float_as_uint(v);
    u = (u & 0x80000000u) ? ~u : (u | 0x80000000u);   // monotone float->uint
    return ((unsigned long long)u << 32) | (unsigned)(0xFFFFFFFFu - (unsigned)sidx);
}

__device__ __forceinline__ void gload16(const void* g, void* l) {
    __builtin_amdgcn_global_load_lds(
        (const __attribute__((address_space(1))) unsigned int*)g,
        (__attribute__((address_space(3))) unsigned int*)l, 16, 0, 0);
}

// K1: partial column sums of support rows (deterministic 2-stage mean)
__global__ void k_partial_mean(const float* __restrict__ sup, float* __restrict__ partial) {
    const int col = threadIdx.x;           // 512
    const int b   = blockIdx.x;            // 100
    const int r0  = b * ROWS_PER_MEAN_BLOCK;
    float acc = 0.0f;
    #pragma unroll 5
    for (int r = 0; r < ROWS_PER_MEAN_BLOCK; ++r)
        acc += sup[(size_t)(r0 + r) * D + col];
    partial[b * D + col] = acc;
}

// K2: finish mean, zero keys
__global__ void k_mean_init(const float* __restrict__ partial, float* __restrict__ mean,
                            unsigned long long* __restrict__ keys) {
    const int col = threadIdx.x;           // 512
    float acc = 0.0f;
    #pragma unroll 4
    for (int b = 0; b < MEAN_BLOCKS; ++b) acc += partial[b * D + col];
    mean[col] = acc * (1.0f / (float)NSUP);
    for (int i = col; i < NSUP; i += 512) keys[i] = 0ull;
}

// K3: center + L2-normalize + scale by 512 + split into fp16 hi/lo.
__global__ void k_split(const float* __restrict__ sup, const float* __restrict__ qry,
                        const float* __restrict__ mean,
                        _Float16* __restrict__ shi, _Float16* __restrict__ slo,
                        _Float16* __restrict__ qhi, _Float16* __restrict__ qlo) {
    const int t    = threadIdx.x;
    const int rloc = t >> 7;               // row within block, 0..3
    const int tc   = t & 127;              // 128 threads per row
    const int b    = (int)blockIdx.x * 4 + rloc;   // global row id 0..10239
    const float* src; _Float16 *dhi, *dlo; int valid;
    if (b < NPAD) { src = sup + (size_t)b * D;
                    dhi = shi + (size_t)b * D; dlo = slo + (size_t)b * D; valid = (b < NSUP); }
    else          { int r = b - NPAD; src = qry + (size_t)r * D;
                    dhi = qhi + (size_t)r * D; dlo = qlo + (size_t)r * D; valid = (r < NQRY); }
    __shared__ float red[8];
    if (!valid) {
        half4v z = {};
        *(half4v*)(dhi + tc * 4) = z;
        *(half4v*)(dlo + tc * 4) = z;
        return;
    }
    float4 v = *(const float4*)(src + tc * 4);
    float4 m = *(const float4*)(mean + tc * 4);
    v.x -= m.x; v.y -= m.y; v.z -= m.z; v.w -= m.w;
    float ss = v.x * v.x + v.y * v.y + v.z * v.z + v.w * v.w;
    #pragma unroll
    for (int off = 32; off > 0; off >>= 1) ss += __shfl_down(ss, off, 64);
    if ((t & 63) == 0) red[t >> 6] = ss;
    __syncthreads();
    const float rn = SCALE / sqrtf(red[rloc * 2] + red[rloc * 2 + 1]);
    float sv[4] = {v.x * rn, v.y * rn, v.z * rn, v.w * rn};
    half4v h, l;
    #pragma unroll
    for (int i = 0; i < 4; ++i) {
        _Float16 hh = (_Float16)sv[i];
        h[i] = hh;
        l[i] = (_Float16)(sv[i] - (float)hh);
    }
    *(half4v*)(dhi + tc * 4) = h;
    *(half4v*)(dlo + tc * 4) = l;
}

// K4: 256x256 tile, 8 waves, wave tile 128x64, BK=32, dbuf LDS (0 conflicts).
// R8's term-ordered counted-vmcnt schedule, merged to 2 phases/tile:
//   A: read ah,bh | stage Shi,Qhi(t+1) | MMA(hh)        | vmcnt(4) -> Slo,Qlo(t) | BAR
//   B: read al,bl | stage Slo,Qlo(t+1) | MMA(lh) MMA(hl)| vmcnt(4) -> Shi,Qhi(t+1) | BAR
// Entry invariant: in-flight = [Slo_t x2, Qlo_t x2]. Peeled tile 15; XCD swizzle.
__launch_bounds__(512, 2)
__global__ void k_main(const _Float16* __restrict__ shi, const _Float16* __restrict__ slo,
                       const _Float16* __restrict__ qhi, const _Float16* __restrict__ qlo,
                       unsigned long long* __restrict__ keys) {
    extern __shared__ char smem[];
    char* lshi = smem + SH_SHI;
    char* lslo = smem + SH_SLO;
    char* lqhi = smem + SH_QHI;
    char* lqlo = smem + SH_QLO;
    unsigned long long* kl = (unsigned long long*)(smem + SH_KL);

    const int tid  = threadIdx.x;
    const int lane = tid & 63;
    const int wv   = tid >> 6;            // 8 waves

    // T1 XCD-aware swizzle: 400 blocks, 400%8==0 -> bijective simple form.
    // XCD k owns 50 contiguous tile-ids -> ~2.5 support panels/XCD (L2 locality).
    const int bid = (int)blockIdx.x;
    const int swz_id = (bid & 7) * 50 + (bid >> 3);
    const int q0 = (swz_id % 20) * 256;
    const int s0 = (swz_id / 20) * 256;
    const int wr   = wv >> 2;             // support half 0/1
    const int wc   = wv & 3;              // query col 0..3

    if (tid < 256) kl[tid] = 0ull;

    // ---- staging addresses (verified R4/R5/R8) ----
    const int srow = wv * 16 + (lane >> 2);                 // chunk0 row 0..127
    const int sl0  = ((lane & 3) ^ ((lane >> 3) & 3)) * 16;
    const size_t gA0 = (size_t)(s0 + srow) * 1024 + sl0;    // +131072 -> rows 128..255
    const size_t gB0 = (size_t)(q0 + srow) * 1024 + sl0;
    const char* pShi = (const char*)shi; const char* pSlo = (const char*)slo;
    const char* pQhi = (const char*)qhi; const char* pQlo = (const char*)qlo;
    const int dst0 = wv * 1024;           // wave-uniform LDS dest (+lane*16 by HW)
    const int dst1 = 8192 + wv * 1024;

    // ---- fragment read bases (verified R4/R5/R8) ----
    const int l15 = lane & 15;
    const int kg  = lane >> 4;
    const int swz = (kg ^ ((l15 >> 1) & 3)) * 16;
    const int foA = (wr * 128 + l15) * 64 + swz;   // + fa*1024 + P*16384
    const int foB = (wc * 64  + l15) * 64 + swz;   // + fb*1024 + P*16384

    f32x4 acc[8][4] = {};

#define BAR()    asm volatile("s_barrier" ::: "memory")
#define WAITV4() asm volatile("s_waitcnt vmcnt(4)" ::: "memory")
#define WAITV0() asm volatile("s_waitcnt vmcnt(0)" ::: "memory")

// stage pair k (k: 0=Shi 1=Slo 2=Qhi 3=Qlo) of tile KT into buffer P
#define ST2(P, KT, K2) do { const size_t kb_ = (size_t)(KT) * 64;           \
        if ((K2) == 0) {                                                    \
            gload16(pShi + gA0 + kb_,          lshi + (P) * 16384 + dst0);  \
            gload16(pShi + gA0 + 131072 + kb_, lshi + (P) * 16384 + dst1);  \
        } else if ((K2) == 1) {                                             \
            gload16(pSlo + gA0 + kb_,          lslo + (P) * 16384 + dst0);  \
            gload16(pSlo + gA0 + 131072 + kb_, lslo + (P) * 16384 + dst1);  \
        } else if ((K2) == 2) {                                             \
            gload16(pQhi + gB0 + kb_,          lqhi + (P) * 16384 + dst0);  \
            gload16(pQhi + gB0 + 131072 + kb_, lqhi + (P) * 16384 + dst1);  \
        } else {                                                            \
            gload16(pQlo + gB0 + kb_,          lqlo + (P) * 16384 + dst0);  \
            gload16(pQlo + gB0 + 131072 + kb_, lqlo + (P) * 16384 + dst1);  \
        } } while (0)

#define RD_AH(P) do { _Pragma("unroll") for (int f = 0; f < 8; ++f)         \
        ah[f] = *(const half8v*)(lshi + (P) * 16384 + foA + f * 1024); } while (0)
#define RD_AL(P) do { _Pragma("unroll") for (int f = 0; f < 8; ++f)         \
        al[f] = *(const half8v*)(lslo + (P) * 16384 + foA + f * 1024); } while (0)
#define RD_BH(P) do { _Pragma("unroll") for (int j = 0; j < 4; ++j)         \
        bh[j] = *(const half8v*)(lqhi + (P) * 16384 + foB + j * 1024); } while (0)
#define RD_BL(P) do { _Pragma("unroll") for (int j = 0; j < 4; ++j)         \
        bl[j] = *(const half8v*)(lqlo + (P) * 16384 + foB + j * 1024); } while (0)

// 32 MFMA: one term (A-array AV x B-array BV) over full wave tile
#define MMA32(AV, BV) do {                                                  \
        __builtin_amdgcn_s_setprio(1);                                      \
        _Pragma("unroll")                                                   \
        for (int fa_ = 0; fa_ < 8; ++fa_)                                   \
        { _Pragma("unroll")                                                 \
          for (int fb_ = 0; fb_ < 4; ++fb_) {                               \
            acc[fa_][fb_] = __builtin_amdgcn_mfma_f32_16x16x32_f16(         \
                AV[fa_], BV[fb_], acc[fa_][fb_], 0, 0, 0);                  \
          } }                                                               \
        __builtin_amdgcn_s_setprio(0);                                      \
        __builtin_amdgcn_sched_barrier(0);                                  \
    } while (0)

    // prologue: stage tile 0 (order Shi,Qhi,Slo,Qlo); certify Shi+Qhi (4 in flight)
    ST2(0, 0, 0); ST2(0, 0, 2); ST2(0, 0, 1); ST2(0, 0, 3);
    WAITV4();
    BAR();

    for (int t = 0; t < 15; ++t) {        // tiles 0..14; tile 15 peeled below
        const int P  = t & 1;
        const int Pn = P ^ 1;
        const int tn = t + 1;
        half8v ah[8], al[8], bh[4], bl[4];

        // phase A: hi*hi
        RD_AH(P); RD_BH(P);
        ST2(Pn, tn, 0); ST2(Pn, tn, 2);   // Shi,Qhi(t+1)  (in-flight: 8)
        MMA32(ah, bh);
        WAITV4();                         // certify Slo(t), Qlo(t)
        BAR();
        // phase B: lo*hi + hi*lo (64-MFMA cluster)
        RD_AL(P); RD_BL(P);
        ST2(Pn, tn, 1); ST2(Pn, tn, 3);   // Slo,Qlo(t+1)  (in-flight: 8)
        MMA32(al, bh);
        MMA32(ah, bl);
        WAITV4();                         // certify Shi,Qhi(t+1); 4 stay in flight
        BAR();
    }
    {   // peeled tile 15 (P=1): no staging; entry in-flight = 4 (Slo15,Qlo15)
        half8v ah[8], al[8], bh[4], bl[4];
        RD_AH(1); RD_BH(1);
        MMA32(ah, bh);
        WAITV0();                         // certify Slo(15), Qlo(15); drained
        BAR();
        RD_AL(1); RD_BL(1);
        MMA32(al, bh);
        MMA32(ah, bl);
    }

#undef MMA32
#undef RD_BL
#undef RD_BH
#undef RD_AL
#undef RD_AH
#undef ST2

    // ---- fused argmax epilogue (verified mapping) ----
    // col(query) = wc*64 + fb*16 + l15 ; row(support) = wr*128 + fa*16 + kg*4 + r
    #pragma unroll
    for (int fb = 0; fb < 4; ++fb) {
        unsigned long long best = 0ull;
        #pragma unroll
        for (int fa = 0; fa < 8; ++fa)
            #pragma unroll
            for (int r = 0; r < 4; ++r) {
                const int s = s0 + wr * 128 + fa * 16 + kg * 4 + r;
                if (s < NSUP) {
                    unsigned long long k = pack_key(acc[fa][fb][r], s);
                    if (k > best) best = k;
                }
            }
        unsigned long long o = __shfl_xor(best, 16, 64); if (o > best) best = o;
        o = __shfl_xor(best, 32, 64);                    if (o > best) best = o;
        if (kg == 0) atomicMax(&kl[wc * 64 + fb * 16 + l15], best);
    }
    __syncthreads();
    if (tid < 256) {
        const int q = q0 + tid;
        if (q < NQRY && kl[tid] != 0ull) atomicMax(&keys[q], kl[tid]);
    }
#undef BAR
#undef WAITV4
#undef WAITV0
}

// K5: decode packed key -> class index
__global__ void k_decode(const unsigned long long* __restrict__ keys, int* __restrict__ out) {
    const int q = blockIdx.x * 256 + threadIdx.x;
    if (q < NQRY) {
        unsigned sidx = 0xFFFFFFFFu - (unsigned)(keys[q] & 0xFFFFFFFFull);
        out[q] = (int)(sidx / 5u);
    }
}

extern "C" void kernel_launch(void* const* d_in, const int* in_sizes, int n_in,
                              void* d_out, int out_size, void* d_ws, size_t ws_size,
                              hipStream_t stream) {
    const float* sup = (const float*)d_in[0];   // [1000,5,512]
    const float* qry = (const float*)d_in[1];   // [5000,512]
    // d_in[2] = use_cosine: after normalization argmin-euclid == argmax-cosine.
    int* out = (int*)d_out;

    char* ws = (char*)d_ws;
    _Float16* shi = (_Float16*)(ws + OFF_SHI);
    _Float16* slo = (_Float16*)(ws + OFF_SLO);
    _Float16* qhi = (_Float16*)(ws + OFF_QHI);
    _Float16* qlo = (_Float16*)(ws + OFF_QLO);
    float* partial = (float*)(ws + OFF_PARTIAL);
    float* mean    = (float*)(ws + OFF_MEAN);
    unsigned long long* keys = (unsigned long long*)(ws + OFF_KEYS);

    static bool attr_set = false;
    if (!attr_set) {
        (void)hipFuncSetAttribute((const void*)k_main,
                                  hipFuncAttributeMaxDynamicSharedMemorySize, SH_TOTAL);
        attr_set = true;
    }

    k_partial_mean<<<MEAN_BLOCKS, 512, 0, stream>>>(sup, partial);
    k_mean_init<<<1, 512, 0, stream>>>(partial, mean, keys);
    k_split<<<(2 * NPAD) / 4, 512, 0, stream>>>(sup, qry, mean, shi, slo, qhi, qlo);
    k_main<<<400, 512, SH_TOTAL, stream>>>(shi, slo, qhi, qlo, keys);
    k_decode<<<(NQRY + 255) / 256, 256, 0, stream>>>(keys, out);
}